// Round 16
// baseline (1008.985 us; speedup 1.0000x reference)
//
#include <hip/hip_runtime.h>

typedef unsigned short u16;
typedef short bf16x8 __attribute__((ext_vector_type(8)));
typedef float f32x4 __attribute__((ext_vector_type(4)));
typedef u16 u16x8 __attribute__((ext_vector_type(8)));

#define SLABH 262144  // h-hi slab elems (256*1024)

__device__ inline u16 f2bf(float f) {
  unsigned u = __float_as_uint(f);
  return (u16)((u + 0x7fffu + ((u >> 16) & 1u)) >> 16);
}
__device__ inline float bf2f(u16 h) { return __uint_as_float(((unsigned)h) << 16); }
__device__ inline float sigf(float x) { return 1.f / (1.f + __expf(-x)); }
__device__ inline float tanh_fast(float x) { return 1.f - 2.f / (__expf(2.f * x) + 1.f); }
// interleaved weight-row R -> original gate-major row (gate in bits 3-4)
__device__ inline int origR2(int R) { return ((R >> 3) & 3) * 1024 + (R >> 5) * 8 + (R & 7); }

__device__ inline void gload_lds16(const u16* g, u16* l) {
  __builtin_amdgcn_global_load_lds(
      (const __attribute__((address_space(1))) void*)g,
      (__attribute__((address_space(3))) void*)l, 16, 0, 0);
}

__device__ __forceinline__ void gbar() { __builtin_amdgcn_s_barrier(); }

template <int N>
__device__ __forceinline__ void waitv() {
  if constexpr (N == 0) asm volatile("s_waitcnt vmcnt(0)" ::: "memory");
  else if constexpr (N == 2) asm volatile("s_waitcnt vmcnt(2)" ::: "memory");
  else if constexpr (N == 4) asm volatile("s_waitcnt vmcnt(4)" ::: "memory");
  else if constexpr (N == 6) asm volatile("s_waitcnt vmcnt(6)" ::: "memory");
  else if constexpr (N == 8) asm volatile("s_waitcnt vmcnt(8)" ::: "memory");
  else if constexpr (N == 16) asm volatile("s_waitcnt vmcnt(16)" ::: "memory");
}

// ============================================================================
// stepk8d: one LSTM step, gates = h_hi @ Beff_hi^T (pure bf16 recurrence),
// fused cell. Proven R15: 512 thr / 8 waves = 2m x 2n x 2K-halves,
// chunk = [Ahi(64)|Bhi(64)] 16 KB/buf, 48 KB LDS traffic/iter,
// vmcnt 4/2/0, masked tail buffer indices. UNCHANGED.
// ============================================================================
__global__ __launch_bounds__(512) void stepk8d(
    const u16* __restrict__ Ahi, const u16* __restrict__ Bhi,
    const float* __restrict__ bias, float* __restrict__ cbuf,
    u16* __restrict__ hhi) {
  constexpr int TSE = 128 * 64;  // 8192 elems = 16 KB per buf
  __shared__ __attribute__((aligned(16))) u16 ts[4 * TSE];  // 64 KB

  const int bid = blockIdx.x, tid = threadIdx.x;
  const int x = bid & 7, i = bid >> 3;
  const int nb = x * 8 + (i & 7);   // XCD x owns nb slice [x*8, x*8+8)
  const int mb = i >> 3;            // 0..3

  const int lane = tid & 63, wid = tid >> 6;     // 8 waves
  const int kh = wid >> 2;                        // K-half 0/1
  const int wrow = ((wid >> 1) & 1) * 32;         // m-half
  const int wcol = (wid & 1) * 32;                // n-half
  const int lr = lane & 15, kq = lane >> 4;
  const int sw0 = (lr & 7) * 16;

  const size_t Aoff = (size_t)mb * 64 * 1024;
  const size_t Boff = (size_t)nb * 64 * 1024;

  // staging: 2 units/thread; unit ui -> buf row r = ui>>3 (0..127),
  // section r>>6: 0=Ahi 1=Bhi; source pre-swizzled, LDS dest linear.
  int uoff[2], usec[2];
#pragma unroll
  for (int u = 0; u < 2; u++) {
    int ui = u * 512 + tid;          // 0..1023
    int r = ui >> 3, j = ui & 7;
    int jp = j ^ (r & 7);
    usec[u] = r >> 6;
    uoff[u] = (r & 63) * 1024 + jp * 8;
  }

  f32x4 acc[2][2];
#pragma unroll
  for (int m = 0; m < 2; m++)
#pragma unroll
    for (int n = 0; n < 2; n++) acc[m][n] = (f32x4)0.f;

  auto STAGE = [&](int buf, int kt) {
    int ko = kt * 64;
    u16* lb = &ts[buf * TSE];
#pragma unroll
    for (int u = 0; u < 2; u++) {
      const u16* src = (usec[u] == 0 ? Ahi + Aoff : Bhi + Boff);
      gload_lds16(src + uoff[u] + ko, lb + (u * 512 + tid) * 8);
    }
  };

  auto COMPUTE = [&](int cur) {
    const char* base = (const char*)&ts[cur * TSE];
    bf16x8 ah[2], bh[2];
    const int so = ((kh * 4 + kq) * 16) ^ sw0;   // this wave's K-half slots
#pragma unroll
    for (int m = 0; m < 2; m++) {
      int row = wrow + m * 16 + lr;
      ah[m] = *(const bf16x8*)(base + row * 128 + so);
    }
#pragma unroll
    for (int n = 0; n < 2; n++) {
      int row = 64 + wcol + n * 16 + lr;
      bh[n] = *(const bf16x8*)(base + row * 128 + so);
    }
#pragma unroll
    for (int m = 0; m < 2; m++)
#pragma unroll
      for (int n = 0; n < 2; n++)
        acc[m][n] = __builtin_amdgcn_mfma_f32_16x16x32_bf16(ah[m], bh[n], acc[m][n], 0, 0, 0);
  };

  // depth-3, 4 bufs; steady vmcnt(4) = 2 stages x 2 loads in flight
  STAGE(0, 0);
  STAGE(1, 1);
  STAGE(2, 2);
  for (int t = 0; t < 13; t++) {
    waitv<4>();
    gbar();
    STAGE((t + 3) & 3, t + 3);
    COMPUTE(t & 3);
  }
  waitv<4>(); gbar(); COMPUTE(13 & 3);
  waitv<2>(); gbar(); COMPUTE(14 & 3);
  waitv<0>(); gbar(); COMPUTE(15 & 3);

  // ---- combine K-half partials + fused LSTM cell ----
  float* g = (float*)ts;  // [2 K-halves][64][65] f32 = 33.3 KB (<= 64 KB)
  constexpr int GR = 64 * 65;
  __syncthreads();
#pragma unroll
  for (int m = 0; m < 2; m++)
#pragma unroll
    for (int n = 0; n < 2; n++)
#pragma unroll
      for (int j = 0; j < 4; j++)
        g[kh * GR + (wrow + m * 16 + kq * 4 + j) * 65 + wcol + n * 16 + lr] = acc[m][n][j];
  __syncthreads();
  // R = nb*64 + rr: gate=(rr>>3)&3, n = nb*16 + (rr>>5)*8 + (rr&7)
  const int n16 = tid & 15;
  const int s = n16 & 7, qd = n16 >> 3;
  const int cbase = qd * 32 + s;
  const float bi = bias[nb * 64 + cbase];
  const float bf = bias[nb * 64 + cbase + 8];
  const float bg = bias[nb * 64 + cbase + 16];
  const float bo = bias[nb * 64 + cbase + 24];
  const int rb = tid >> 4;  // 0..31
#pragma unroll
  for (int i2 = 0; i2 < 2; i2++) {
    int br = rb + i2 * 32;
    const float* g0 = g + br * 65;
    const float* g1 = g + GR + br * 65;
    float xi = g0[cbase] + g1[cbase] + bi;
    float xf = g0[cbase + 8] + g1[cbase + 8] + bf;
    float xg = g0[cbase + 16] + g1[cbase + 16] + bg;
    float xo = g0[cbase + 24] + g1[cbase + 24] + bo;
    int b = mb * 64 + br;
    int col = nb * 16 + n16;
    int cidx = b * 1024 + col;
    float cn = sigf(xf) * cbuf[cidx] + sigf(xi) * tanh_fast(xg);
    float h = sigf(xo) * tanh_fast(cn);
    cbuf[cidx] = cn;
    hhi[cidx] = f2bf(h);
  }
}

// ============================================================================
// gemmk: general LDS-staged GEMM (W_c prep, step 0, y-GEMM).
// R16: new SWZ=4 for the BM=64 y-GEMM — XCD owns contiguous mb slice,
// nb innermost (A-tile shared by 16 consecutive same-XCD blocks -> L2-hot).
// ============================================================================
template <int BM, int BN, int NT, int MODE, int EPI, int SWZ, int NBW>
__global__ __launch_bounds__(256) void gemmk(
    const u16* __restrict__ A0p, const u16* __restrict__ A1p,
    const u16* __restrict__ A2p, const u16* __restrict__ A3p,
    const u16* __restrict__ B0p, const u16* __restrict__ B1p,
    const u16* __restrict__ B2p, const u16* __restrict__ B3p,
    const float* __restrict__ bias, float* __restrict__ cbuf,
    u16* __restrict__ hhi, u16* __restrict__ hlo, float* __restrict__ fout) {
  constexpr int ROWS = (MODE == 2) ? (BM + BN) : 2 * (BM + BN);
  constexpr int TSE = ROWS * 64;
  constexpr int UNITS = ROWS / 32;  // 16B units per thread per stage
  constexpr int MR = BM / 32;
  constexpr int NR = BN / 32;

  __shared__ __attribute__((aligned(16))) u16 ts[4 * TSE];

  const int bid = blockIdx.x, tid = threadIdx.x;
  int mb, nb;
  if constexpr (SWZ == 1) {
    int x = bid & 7, i = bid >> 3;
    nb = x * 8 + (i & 7);
    mb = i >> 3;
  } else if constexpr (SWZ == 2) {
    int x = bid & 7, i = bid >> 3;
    nb = i & 7;
    mb = x * 32 + (i >> 3);
  } else if constexpr (SWZ == 3) {
    int x = bid & 7, i = bid >> 3;
    int g = i >> 6, r = i & 63;
    mb = x * 8 + g * 64 + (r >> 3);
    nb = r & 7;
  } else if constexpr (SWZ == 4) {  // y BM=64: XCD owns 64-wide mb slice
    int x = bid & 7, i = bid >> 3;
    nb = i & 15;
    mb = x * 64 + (i >> 4);
  } else {
    nb = bid % NBW;
    mb = bid / NBW;
  }

  const int lane = tid & 63, wid = tid >> 6;
  const int wrow = (wid >> 1) * (BM / 2);
  const int wcol = (wid & 1) * (BN / 2);
  const int lr = lane & 15, kq = lane >> 4;

  const size_t Aoff = (size_t)mb * BM * 1024;
  const size_t Boff = (size_t)nb * BN * 1024;
  const int tid3 = tid >> 3;
  const int jp = (tid & 7) ^ (tid3 & 7);

  f32x4 acc[MR][NR];
#pragma unroll
  for (int m = 0; m < MR; m++)
#pragma unroll
    for (int n = 0; n < NR; n++) acc[m][n] = (f32x4)0.f;

  auto STAGE = [&](int buf, int kt) {
    const u16 *a0, *a1, *b0, *b1;
    int ko;
    if constexpr (MODE == 1) {
      if (kt >= NT / 2) { a0 = A2p; a1 = A3p; b0 = B2p; b1 = B3p; ko = (kt - NT / 2) * 64; }
      else { a0 = A0p; a1 = A1p; b0 = B0p; b1 = B1p; ko = kt * 64; }
    } else {
      a0 = A0p; a1 = A1p; b0 = B0p; b1 = B1p; ko = kt * 64;
    }
    u16* lb = &ts[buf * TSE];
#pragma unroll
    for (int u = 0; u < UNITS; u++) {
      const u16* src;
      int prow;
      if constexpr (MODE == 2) {
        if (u < BM / 32) { src = a0 + Aoff; prow = u * 32 + tid3; }
        else { src = b0 + Boff; prow = (u - BM / 32) * 32 + tid3; }
      } else {
        int s = u >> 1;
        src = (s == 0 ? a0 + Aoff : s == 1 ? a1 + Aoff : s == 2 ? b0 + Boff : b1 + Boff);
        prow = (u & 1) * 32 + tid3;
      }
      gload_lds16(src + prow * 1024 + jp * 8 + ko, lb + (u * 256 + tid) * 8);
    }
  };

  auto COMPUTE = [&](int cur) {
    const char* base = (const char*)&ts[cur * TSE];
    int sw0 = (lr & 7) * 16;
    if constexpr (MODE == 2) {
      bf16x8 a[MR][2], b[NR][2];
#pragma unroll
      for (int m = 0; m < MR; m++)
#pragma unroll
        for (int kh = 0; kh < 2; kh++) {
          int row = wrow + m * 16 + lr;
          a[m][kh] = *(const bf16x8*)(base + row * 128 + (((kh * 4 + kq) * 16) ^ sw0));
        }
#pragma unroll
      for (int n = 0; n < NR; n++)
#pragma unroll
        for (int kh = 0; kh < 2; kh++) {
          int row = BM + wcol + n * 16 + lr;
          b[n][kh] = *(const bf16x8*)(base + row * 128 + (((kh * 4 + kq) * 16) ^ sw0));
        }
#pragma unroll
      for (int kh = 0; kh < 2; kh++)
#pragma unroll
        for (int m = 0; m < MR; m++)
#pragma unroll
          for (int n = 0; n < NR; n++)
            acc[m][n] = __builtin_amdgcn_mfma_f32_16x16x32_bf16(a[m][kh], b[n][kh], acc[m][n], 0, 0, 0);
    } else {
      bf16x8 ah[2][2], al[2][2], bh[2][2], bl[2][2];
#pragma unroll
      for (int m = 0; m < 2; m++)
#pragma unroll
        for (int kh = 0; kh < 2; kh++) {
          int row = wrow + m * 16 + lr;
          int so = ((kh * 4 + kq) * 16) ^ sw0;
          ah[m][kh] = *(const bf16x8*)(base + row * 128 + so);
          al[m][kh] = *(const bf16x8*)(base + (row + 64) * 128 + so);
        }
#pragma unroll
      for (int n = 0; n < 2; n++)
#pragma unroll
        for (int kh = 0; kh < 2; kh++) {
          int row = 128 + wcol + n * 16 + lr;
          int so = ((kh * 4 + kq) * 16) ^ sw0;
          bh[n][kh] = *(const bf16x8*)(base + row * 128 + so);
          bl[n][kh] = *(const bf16x8*)(base + (row + 64) * 128 + so);
        }
#pragma unroll
      for (int kh = 0; kh < 2; kh++)
#pragma unroll
        for (int m = 0; m < 2; m++)
#pragma unroll
          for (int n = 0; n < 2; n++) {
            acc[m][n] = __builtin_amdgcn_mfma_f32_16x16x32_bf16(ah[m][kh], bh[n][kh], acc[m][n], 0, 0, 0);
            acc[m][n] = __builtin_amdgcn_mfma_f32_16x16x32_bf16(al[m][kh], bh[n][kh], acc[m][n], 0, 0, 0);
            acc[m][n] = __builtin_amdgcn_mfma_f32_16x16x32_bf16(ah[m][kh], bl[n][kh], acc[m][n], 0, 0, 0);
          }
    }
  };

  STAGE(0, 0);
  STAGE(1, 1);
  STAGE(2, 2);
  for (int t = 0; t < NT - 3; t++) {
    waitv<2 * UNITS>();
    gbar();
    STAGE((t + 3) & 3, t + 3);
    COMPUTE(t & 3);
  }
  waitv<2 * UNITS>(); gbar(); COMPUTE((NT - 3) & 3);
  waitv<UNITS>();     gbar(); COMPUTE((NT - 2) & 3);
  waitv<0>();         gbar(); COMPUTE((NT - 1) & 3);

  if constexpr (EPI == 0 || EPI == 2) {
    float* Cb = fout + (size_t)(mb * BM + wrow) * 1024 + nb * BN + wcol;
#pragma unroll
    for (int n = 0; n < NR; n++) {
      float blv = (EPI == 2) ? bias[nb * BN + wcol + n * 16 + lr] : 0.f;
#pragma unroll
      for (int m = 0; m < MR; m++)
#pragma unroll
        for (int j = 0; j < 4; j++)
          Cb[(size_t)(m * 16 + kq * 4 + j) * 1024 + n * 16 + lr] = acc[m][n][j] + blv;
    }
  } else if constexpr (EPI == 3) {
    float* Cb = fout + (size_t)(mb * BM + wrow) * 1024 + nb * BN + wcol;
    const int t = (mb * BM) >> 8;
#pragma unroll
    for (int n = 0; n < NR; n++) {
      float s = 0.f, s2 = 0.f;
#pragma unroll
      for (int m = 0; m < MR; m++)
#pragma unroll
        for (int j = 0; j < 4; j++) {
          float v = acc[m][n][j];
          Cb[(size_t)(m * 16 + kq * 4 + j) * 1024 + n * 16 + lr] = v;
          s += v;
          s2 += v * v;
        }
      s += __shfl_xor(s, 16);  s += __shfl_xor(s, 32);
      s2 += __shfl_xor(s2, 16); s2 += __shfl_xor(s2, 32);
      if (kq == 0) {
        int col = nb * BN + wcol + n * 16 + lr;
        atomicAdd(&cbuf[t * 1024 + col], s);
        atomicAdd(&cbuf[131072 + t * 1024 + col], s2);
      }
    }
  } else {
    float* g = (float*)ts;
    __syncthreads();
#pragma unroll
    for (int m = 0; m < 2; m++)
#pragma unroll
      for (int n = 0; n < 2; n++)
#pragma unroll
        for (int j = 0; j < 4; j++)
          g[(wrow + m * 16 + kq * 4 + j) * 65 + wcol + n * 16 + lr] = acc[m][n][j];
    __syncthreads();
    const int n16 = tid & 15;
    const int s = n16 & 7, q = n16 >> 3;
    const int cbase = q * 32 + s;
    const float bi = bias[nb * 64 + cbase];
    const float bf = bias[nb * 64 + cbase + 8];
    const float bg = bias[nb * 64 + cbase + 16];
    const float bo = bias[nb * 64 + cbase + 24];
#pragma unroll
    for (int i2 = 0; i2 < 4; i2++) {
      int br = (tid >> 4) + i2 * 16;
      float xi = g[br * 65 + cbase] + bi;
      float xf = g[br * 65 + cbase + 8] + bf;
      float xg = g[br * 65 + cbase + 16] + bg;
      float xo = g[br * 65 + cbase + 24] + bo;
      int b = mb * 64 + br;
      int col = nb * 16 + n16;
      int cidx = b * 1024 + col;
      float cn = sigf(xf) * cbuf[cidx] + sigf(xi) * tanh_fast(xg);
      float h = sigf(xo) * tanh_fast(cn);
      cbuf[cidx] = cn;
      u16 hi = f2bf(h);
      u16 lo = f2bf(h - bf2f(hi));
      hhi[cidx] = hi;
      hlo[cidx] = lo;
    }
  }
}

// ---- prep kernels (planes pitch 1024) ----

template <bool IMAP, bool WLO>
__global__ __launch_bounds__(256) void prep_split(const float* __restrict__ src,
                                                  u16* __restrict__ hi_p,
                                                  u16* __restrict__ lo_p) {
  int i = blockIdx.x * 256 + threadIdx.x;
  int r = i >> 7, k8 = (i & 127) << 3;
  int orig = IMAP ? origR2(r) : r;
  const float* s = src + (size_t)orig * 1024 + k8;
  u16x8 oh, ol;
#pragma unroll
  for (int e = 0; e < 8; e++) {
    float f = s[e];
    u16 h = f2bf(f);
    oh[e] = h;
    if constexpr (WLO) ol[e] = f2bf(f - bf2f(h));
  }
  *(u16x8*)&hi_p[(size_t)r * 1024 + k8] = oh;
  if constexpr (WLO) *(u16x8*)&lo_p[(size_t)r * 1024 + k8] = ol;
}

__global__ __launch_bounds__(256) void prep_wlt(const float* __restrict__ W,
                                                u16* __restrict__ hi_p,
                                                u16* __restrict__ lo_p) {
  int i = blockIdx.x * 256 + threadIdx.x;
  int k = i >> 7, j8 = (i & 127) << 3;
  u16x8 oh, ol;
#pragma unroll
  for (int e = 0; e < 8; e++) {
    float f = W[(size_t)(j8 + e) * 1024 + k];
    u16 h = f2bf(f);
    oh[e] = h;
    ol[e] = f2bf(f - bf2f(h));
  }
  *(u16x8*)&hi_p[(size_t)k * 1024 + j8] = oh;
  *(u16x8*)&lo_p[(size_t)k * 1024 + j8] = ol;
}

// Beff_hi[R] = bf16(Wc_f32[R] + W_hh[origR2(R)])  (hi plane only)
__global__ __launch_bounds__(256) void prep_beff(const float* __restrict__ Wc,
                                                 const float* __restrict__ Whh,
                                                 u16* __restrict__ hi_p) {
  int i = blockIdx.x * 256 + threadIdx.x;
  int r = i >> 7, k8 = (i & 127) << 3;
  const float* s1 = Wc + (size_t)r * 1024 + k8;
  const float* s2 = Whh + (size_t)origR2(r) * 1024 + k8;
  u16x8 oh;
#pragma unroll
  for (int e = 0; e < 8; e++) oh[e] = f2bf(s1[e] + s2[e]);
  *(u16x8*)&hi_p[(size_t)r * 1024 + k8] = oh;
}

__global__ __launch_bounds__(256) void prep_a0(const float* __restrict__ x0,
                                               const float* __restrict__ h0,
                                               const float* __restrict__ c0,
                                               u16* __restrict__ xhi, u16* __restrict__ xlo,
                                               u16* __restrict__ hhi, u16* __restrict__ hlo,
                                               float* __restrict__ cbuf) {
  int i = blockIdx.x * 256 + threadIdx.x;
  int sel = i >> 15, ii = i & 32767;
  int r = ii >> 7, k8 = (ii & 127) << 3;
  const float* s = (sel ? h0 : x0) + r * 1024 + k8;
  u16* hp = (sel ? hhi : xhi) + r * 1024 + k8;
  u16* lp = (sel ? hlo : xlo) + r * 1024 + k8;
  u16x8 oh, ol;
#pragma unroll
  for (int e = 0; e < 8; e++) {
    float f = s[e];
    u16 h = f2bf(f);
    oh[e] = h;
    ol[e] = f2bf(f - bf2f(h));
  }
  *(u16x8*)hp = oh;
  *(u16x8*)lp = ol;
  if (i < 32768) {
    float4 v0 = *(const float4*)&c0[i * 8];
    float4 v1 = *(const float4*)&c0[i * 8 + 4];
    *(float4*)&cbuf[i * 8] = v0;
    *(float4*)&cbuf[i * 8 + 4] = v1;
  }
}

__global__ __launch_bounds__(256) void prep_bias(const float* __restrict__ Wih,
                                                 const float* __restrict__ b_ih,
                                                 const float* __restrict__ b_hh,
                                                 const float* __restrict__ b_lin,
                                                 float* __restrict__ bc0,
                                                 float* __restrict__ bc1) {
  int wid = threadIdx.x >> 6, lane = threadIdx.x & 63;
  int R = blockIdx.x * 4 + wid;
  int o = origR2(R);
  float p = 0.f;
#pragma unroll
  for (int it = 0; it < 16; it++) p += Wih[(size_t)o * 1024 + lane + it * 64] * b_lin[lane + it * 64];
#pragma unroll
  for (int m = 1; m < 64; m <<= 1) p += __shfl_xor(p, m);
  if (lane == 0) {
    float s = b_ih[o] + b_hh[o];
    bc0[R] = s;
    bc1[R] = s + p;
  }
}

// Normalize in place using precomputed stats (S | S2).
__global__ __launch_bounds__(256) void bn_norm(const float* __restrict__ stats,
                                               float* __restrict__ out) {
  int t = blockIdx.x >> 1, bh = blockIdx.x & 1;
  int d = threadIdx.x << 2;
  const float* sp = stats + t * 1024 + d;
  const float* sp2 = stats + 131072 + t * 1024 + d;
  float mean[4], rs[4];
#pragma unroll
  for (int e = 0; e < 4; e++) {
    float mn = sp[e] * (1.f / 256.f);
    float var = fmaxf(sp2[e] * (1.f / 256.f) - mn * mn, 0.f);
    mean[e] = mn;
    rs[e] = rsqrtf(var + 1e-5f);
  }
  float* base = out + (size_t)t * 262144 + bh * 131072 + d;
#pragma unroll 4
  for (int b = 0; b < 128; b++) {
    float4 v = *(float4*)(base + b * 1024);
    v.x = (v.x - mean[0]) * rs[0];
    v.y = (v.y - mean[1]) * rs[1];
    v.z = (v.z - mean[2]) * rs[2];
    v.w = (v.w - mean[3]) * rs[3];
    *(float4*)(base + b * 1024) = v;
  }
}

extern "C" void kernel_launch(void* const* d_in, const int* in_sizes, int n_in,
                              void* d_out, int out_size, void* d_ws, size_t ws_size,
                              hipStream_t stream) {
  const float* inputs = (const float*)d_in[0];
  const float* W_ih = (const float*)d_in[1];
  const float* W_hh = (const float*)d_in[2];
  const float* b_ih = (const float*)d_in[3];
  const float* b_hh = (const float*)d_in[4];
  const float* W_lin = (const float*)d_in[5];
  const float* b_lin = (const float*)d_in[6];
  const float* h0 = (const float*)d_in[7];
  const float* c0 = (const float*)d_in[8];
  float* out = (float*)d_out;

  char* ws = (char*)d_ws;
  float* bc0 = (float*)(ws + 0);             // 16,384
  float* bc1 = (float*)(ws + 16384);         // 16,384
  float* cbuf = (float*)(ws + 32768);        // 1,048,576
  u16* Wlin_hi = (u16*)(ws + 1081344);       // 2,097,152
  u16* Beff_hi = (u16*)(ws + 3178496);       // 8,388,608
  u16* xhi = (u16*)(ws + 19955712);          // 524,288
  u16* xlo = (u16*)(ws + 20480000);          // 524,288
  u16* h0hi = (u16*)(ws + 21004288);         // 524,288
  u16* h0lo = (u16*)(ws + 21528576);         // 524,288
  u16* Hlo0 = (u16*)(ws + 22052864);         // 524,288 (step0 writes; unused after)
  u16* Hhi = (u16*)(ws + 23101440);          // 67,108,864 (128 slabs of 512KB)
  // transients aliased inside Hhi (dead after prep / step 0):
  u16* Whh_hi = (u16*)(ws + 23101440 + 2097152);    // slabs 4..19
  u16* Whh_lo = (u16*)(ws + 23101440 + 10485760);   // slabs 20..35
  u16* Wih_hi = (u16*)(ws + 23101440 + 18874368);   // slabs 36..51
  u16* Wih_lo = (u16*)(ws + 23101440 + 27262976);   // slabs 52..67
  u16* Wlt_hi = (u16*)(ws + 23101440 + 35651584);   // slabs 68..71
  u16* Wlt_lo = (u16*)(ws + 23101440 + 37748736);   // slabs 72..75
  float* Wc_f32 = (float*)(ws + 23101440 + 39845888);  // slabs 76..107
  float* stats = (float*)(ws + 90210304);    // 1,048,576 (S | S2)

  hipMemsetAsync(stats, 0, 1048576, stream);
  prep_split<true, true><<<2048, 256, 0, stream>>>(W_ih, Wih_hi, Wih_lo);
  prep_split<true, true><<<2048, 256, 0, stream>>>(W_hh, Whh_hi, Whh_lo);
  prep_split<false, false><<<512, 256, 0, stream>>>(W_lin, Wlin_hi, nullptr);
  prep_wlt<<<512, 256, 0, stream>>>(W_lin, Wlt_hi, Wlt_lo);
  prep_a0<<<256, 256, 0, stream>>>(inputs, h0, c0, xhi, xlo, h0hi, h0lo, cbuf);
  prep_bias<<<1024, 256, 0, stream>>>(W_ih, b_ih, b_hh, b_lin, bc0, bc1);

  // W_c = W_ih @ W_lin (bf16x3), rows interleaved. M=4096, N=1024, K=1024.
  gemmk<64, 64, 16, 0, 0, 0, 16><<<1024, 256, 0, stream>>>(
      Wih_hi, Wih_lo, nullptr, nullptr, Wlt_hi, Wlt_lo, nullptr, nullptr,
      nullptr, nullptr, nullptr, nullptr, Wc_f32);
  prep_beff<<<2048, 256, 0, stream>>>(Wc_f32, W_hh, Beff_hi);

  // step 0: gates from (x0,h0): two K-phases (x @ Wih, h @ Whh), K=2048 total.
  gemmk<64, 64, 32, 1, 1, 1, 0><<<256, 256, 0, stream>>>(
      xhi, xlo, h0hi, h0lo, Wih_hi, Wih_lo, Whh_hi, Whh_lo,
      bc0, cbuf, Hhi, Hlo0, nullptr);
  // steps 1..127: pure-bf16 stepk8d, gates = h_hi @ Beff_hi.
  for (int t = 1; t < 128; t++) {
    stepk8d<<<256, 512, 0, stream>>>(
        Hhi + (size_t)(t - 1) * SLABH, Beff_hi, bc1, cbuf,
        Hhi + (size_t)t * SLABH);
  }

  // ys' = Hs_hi @ W_lin_hi^T (b_lin cancels in BN). Stats in epilogue.
  // BM=BN=64 -> 2 blocks/CU; SWZ=4: XCD-sliced mb, nb innermost (A L2-hot).
  gemmk<64, 64, 16, 2, 3, 4, 16><<<8192, 256, 0, stream>>>(
      Hhi, nullptr, nullptr, nullptr, Wlin_hi, nullptr, nullptr, nullptr,
      nullptr, stats, nullptr, nullptr, out);
  bn_norm<<<256, 256, 0, stream>>>(stats, out);
}

// Round 17
// 964.338 us; speedup vs baseline: 1.0463x; 1.0463x over previous
//
#include <hip/hip_runtime.h>

typedef unsigned short u16;
typedef short bf16x8 __attribute__((ext_vector_type(8)));
typedef float f32x4 __attribute__((ext_vector_type(4)));
typedef u16 u16x8 __attribute__((ext_vector_type(8)));

#define SLABH 262144  // h-hi slab elems (256*1024)

__device__ inline u16 f2bf(float f) {
  unsigned u = __float_as_uint(f);
  return (u16)((u + 0x7fffu + ((u >> 16) & 1u)) >> 16);
}
__device__ inline float bf2f(u16 h) { return __uint_as_float(((unsigned)h) << 16); }
__device__ inline float sigf(float x) { return 1.f / (1.f + __expf(-x)); }
__device__ inline float tanh_fast(float x) { return 1.f - 2.f / (__expf(2.f * x) + 1.f); }
// interleaved weight-row R -> original gate-major row (gate in bits 3-4)
__device__ inline int origR2(int R) { return ((R >> 3) & 3) * 1024 + (R >> 5) * 8 + (R & 7); }

__device__ inline void gload_lds16(const u16* g, u16* l) {
  __builtin_amdgcn_global_load_lds(
      (const __attribute__((address_space(1))) void*)g,
      (__attribute__((address_space(3))) void*)l, 16, 0, 0);
}

__device__ __forceinline__ void gbar() { __builtin_amdgcn_s_barrier(); }

template <int N>
__device__ __forceinline__ void waitv() {
  if constexpr (N == 0) asm volatile("s_waitcnt vmcnt(0)" ::: "memory");
  else if constexpr (N == 2) asm volatile("s_waitcnt vmcnt(2)" ::: "memory");
  else if constexpr (N == 4) asm volatile("s_waitcnt vmcnt(4)" ::: "memory");
  else if constexpr (N == 6) asm volatile("s_waitcnt vmcnt(6)" ::: "memory");
  else if constexpr (N == 8) asm volatile("s_waitcnt vmcnt(8)" ::: "memory");
  else if constexpr (N == 16) asm volatile("s_waitcnt vmcnt(16)" ::: "memory");
}

// ============================================================================
// stepk8d: one LSTM step, gates = h_hi @ Beff_hi^T (pure bf16 recurrence),
// fused cell. Proven R15/R16. UNCHANGED.
// ============================================================================
__global__ __launch_bounds__(512) void stepk8d(
    const u16* __restrict__ Ahi, const u16* __restrict__ Bhi,
    const float* __restrict__ bias, float* __restrict__ cbuf,
    u16* __restrict__ hhi) {
  constexpr int TSE = 128 * 64;  // 8192 elems = 16 KB per buf
  __shared__ __attribute__((aligned(16))) u16 ts[4 * TSE];  // 64 KB

  const int bid = blockIdx.x, tid = threadIdx.x;
  const int x = bid & 7, i = bid >> 3;
  const int nb = x * 8 + (i & 7);   // XCD x owns nb slice [x*8, x*8+8)
  const int mb = i >> 3;            // 0..3

  const int lane = tid & 63, wid = tid >> 6;     // 8 waves
  const int kh = wid >> 2;                        // K-half 0/1
  const int wrow = ((wid >> 1) & 1) * 32;         // m-half
  const int wcol = (wid & 1) * 32;                // n-half
  const int lr = lane & 15, kq = lane >> 4;
  const int sw0 = (lr & 7) * 16;

  const size_t Aoff = (size_t)mb * 64 * 1024;
  const size_t Boff = (size_t)nb * 64 * 1024;

  // staging: 2 units/thread; unit ui -> buf row r = ui>>3 (0..127),
  // section r>>6: 0=Ahi 1=Bhi; source pre-swizzled, LDS dest linear.
  int uoff[2], usec[2];
#pragma unroll
  for (int u = 0; u < 2; u++) {
    int ui = u * 512 + tid;          // 0..1023
    int r = ui >> 3, j = ui & 7;
    int jp = j ^ (r & 7);
    usec[u] = r >> 6;
    uoff[u] = (r & 63) * 1024 + jp * 8;
  }

  f32x4 acc[2][2];
#pragma unroll
  for (int m = 0; m < 2; m++)
#pragma unroll
    for (int n = 0; n < 2; n++) acc[m][n] = (f32x4)0.f;

  auto STAGE = [&](int buf, int kt) {
    int ko = kt * 64;
    u16* lb = &ts[buf * TSE];
#pragma unroll
    for (int u = 0; u < 2; u++) {
      const u16* src = (usec[u] == 0 ? Ahi + Aoff : Bhi + Boff);
      gload_lds16(src + uoff[u] + ko, lb + (u * 512 + tid) * 8);
    }
  };

  auto COMPUTE = [&](int cur) {
    const char* base = (const char*)&ts[cur * TSE];
    bf16x8 ah[2], bh[2];
    const int so = ((kh * 4 + kq) * 16) ^ sw0;   // this wave's K-half slots
#pragma unroll
    for (int m = 0; m < 2; m++) {
      int row = wrow + m * 16 + lr;
      ah[m] = *(const bf16x8*)(base + row * 128 + so);
    }
#pragma unroll
    for (int n = 0; n < 2; n++) {
      int row = 64 + wcol + n * 16 + lr;
      bh[n] = *(const bf16x8*)(base + row * 128 + so);
    }
#pragma unroll
    for (int m = 0; m < 2; m++)
#pragma unroll
      for (int n = 0; n < 2; n++)
        acc[m][n] = __builtin_amdgcn_mfma_f32_16x16x32_bf16(ah[m], bh[n], acc[m][n], 0, 0, 0);
  };

  // depth-3, 4 bufs; steady vmcnt(4) = 2 stages x 2 loads in flight
  STAGE(0, 0);
  STAGE(1, 1);
  STAGE(2, 2);
  for (int t = 0; t < 13; t++) {
    waitv<4>();
    gbar();
    STAGE((t + 3) & 3, t + 3);
    COMPUTE(t & 3);
  }
  waitv<4>(); gbar(); COMPUTE(13 & 3);
  waitv<2>(); gbar(); COMPUTE(14 & 3);
  waitv<0>(); gbar(); COMPUTE(15 & 3);

  // ---- combine K-half partials + fused LSTM cell ----
  float* g = (float*)ts;  // [2 K-halves][64][65] f32 = 33.3 KB (<= 64 KB)
  constexpr int GR = 64 * 65;
  __syncthreads();
#pragma unroll
  for (int m = 0; m < 2; m++)
#pragma unroll
    for (int n = 0; n < 2; n++)
#pragma unroll
      for (int j = 0; j < 4; j++)
        g[kh * GR + (wrow + m * 16 + kq * 4 + j) * 65 + wcol + n * 16 + lr] = acc[m][n][j];
  __syncthreads();
  // R = nb*64 + rr: gate=(rr>>3)&3, n = nb*16 + (rr>>5)*8 + (rr&7)
  const int n16 = tid & 15;
  const int s = n16 & 7, qd = n16 >> 3;
  const int cbase = qd * 32 + s;
  const float bi = bias[nb * 64 + cbase];
  const float bf = bias[nb * 64 + cbase + 8];
  const float bg = bias[nb * 64 + cbase + 16];
  const float bo = bias[nb * 64 + cbase + 24];
  const int rb = tid >> 4;  // 0..31
#pragma unroll
  for (int i2 = 0; i2 < 2; i2++) {
    int br = rb + i2 * 32;
    const float* g0 = g + br * 65;
    const float* g1 = g + GR + br * 65;
    float xi = g0[cbase] + g1[cbase] + bi;
    float xf = g0[cbase + 8] + g1[cbase + 8] + bf;
    float xg = g0[cbase + 16] + g1[cbase + 16] + bg;
    float xo = g0[cbase + 24] + g1[cbase + 24] + bo;
    int b = mb * 64 + br;
    int col = nb * 16 + n16;
    int cidx = b * 1024 + col;
    float cn = sigf(xf) * cbuf[cidx] + sigf(xi) * tanh_fast(xg);
    float h = sigf(xo) * tanh_fast(cn);
    cbuf[cidx] = cn;
    hhi[cidx] = f2bf(h);
  }
}

// ============================================================================
// gemmk: general LDS-staged GEMM (W_c prep, step 0, y-GEMM). As R16.
// ============================================================================
template <int BM, int BN, int NT, int MODE, int EPI, int SWZ, int NBW>
__global__ __launch_bounds__(256) void gemmk(
    const u16* __restrict__ A0p, const u16* __restrict__ A1p,
    const u16* __restrict__ A2p, const u16* __restrict__ A3p,
    const u16* __restrict__ B0p, const u16* __restrict__ B1p,
    const u16* __restrict__ B2p, const u16* __restrict__ B3p,
    const float* __restrict__ bias, float* __restrict__ cbuf,
    u16* __restrict__ hhi, u16* __restrict__ hlo, float* __restrict__ fout) {
  constexpr int ROWS = (MODE == 2) ? (BM + BN) : 2 * (BM + BN);
  constexpr int TSE = ROWS * 64;
  constexpr int UNITS = ROWS / 32;  // 16B units per thread per stage
  constexpr int MR = BM / 32;
  constexpr int NR = BN / 32;

  __shared__ __attribute__((aligned(16))) u16 ts[4 * TSE];

  const int bid = blockIdx.x, tid = threadIdx.x;
  int mb, nb;
  if constexpr (SWZ == 1) {
    int x = bid & 7, i = bid >> 3;
    nb = x * 8 + (i & 7);
    mb = i >> 3;
  } else if constexpr (SWZ == 2) {  // y BM=128: XCD owns 32-wide mb slice
    int x = bid & 7, i = bid >> 3;
    nb = i & 7;
    mb = x * 32 + (i >> 3);
  } else if constexpr (SWZ == 4) {  // y BM=64: XCD owns 64-wide mb slice
    int x = bid & 7, i = bid >> 3;
    nb = i & 15;
    mb = x * 64 + (i >> 4);
  } else {
    nb = bid % NBW;
    mb = bid / NBW;
  }

  const int lane = tid & 63, wid = tid >> 6;
  const int wrow = (wid >> 1) * (BM / 2);
  const int wcol = (wid & 1) * (BN / 2);
  const int lr = lane & 15, kq = lane >> 4;

  const size_t Aoff = (size_t)mb * BM * 1024;
  const size_t Boff = (size_t)nb * BN * 1024;
  const int tid3 = tid >> 3;
  const int jp = (tid & 7) ^ (tid3 & 7);

  f32x4 acc[MR][NR];
#pragma unroll
  for (int m = 0; m < MR; m++)
#pragma unroll
    for (int n = 0; n < NR; n++) acc[m][n] = (f32x4)0.f;

  auto STAGE = [&](int buf, int kt) {
    const u16 *a0, *a1, *b0, *b1;
    int ko;
    if constexpr (MODE == 1) {
      if (kt >= NT / 2) { a0 = A2p; a1 = A3p; b0 = B2p; b1 = B3p; ko = (kt - NT / 2) * 64; }
      else { a0 = A0p; a1 = A1p; b0 = B0p; b1 = B1p; ko = kt * 64; }
    } else {
      a0 = A0p; a1 = A1p; b0 = B0p; b1 = B1p; ko = kt * 64;
    }
    u16* lb = &ts[buf * TSE];
#pragma unroll
    for (int u = 0; u < UNITS; u++) {
      const u16* src;
      int prow;
      if constexpr (MODE == 2) {
        if (u < BM / 32) { src = a0 + Aoff; prow = u * 32 + tid3; }
        else { src = b0 + Boff; prow = (u - BM / 32) * 32 + tid3; }
      } else {
        int s = u >> 1;
        src = (s == 0 ? a0 + Aoff : s == 1 ? a1 + Aoff : s == 2 ? b0 + Boff : b1 + Boff);
        prow = (u & 1) * 32 + tid3;
      }
      gload_lds16(src + prow * 1024 + jp * 8 + ko, lb + (u * 256 + tid) * 8);
    }
  };

  auto COMPUTE = [&](int cur) {
    const char* base = (const char*)&ts[cur * TSE];
    int sw0 = (lr & 7) * 16;
    if constexpr (MODE == 2) {
      bf16x8 a[MR][2], b[NR][2];
#pragma unroll
      for (int m = 0; m < MR; m++)
#pragma unroll
        for (int kh = 0; kh < 2; kh++) {
          int row = wrow + m * 16 + lr;
          a[m][kh] = *(const bf16x8*)(base + row * 128 + (((kh * 4 + kq) * 16) ^ sw0));
        }
#pragma unroll
      for (int n = 0; n < NR; n++)
#pragma unroll
        for (int kh = 0; kh < 2; kh++) {
          int row = BM + wcol + n * 16 + lr;
          b[n][kh] = *(const bf16x8*)(base + row * 128 + (((kh * 4 + kq) * 16) ^ sw0));
        }
#pragma unroll
      for (int kh = 0; kh < 2; kh++)
#pragma unroll
        for (int m = 0; m < MR; m++)
#pragma unroll
          for (int n = 0; n < NR; n++)
            acc[m][n] = __builtin_amdgcn_mfma_f32_16x16x32_bf16(a[m][kh], b[n][kh], acc[m][n], 0, 0, 0);
    } else {
      bf16x8 ah[2][2], al[2][2], bh[2][2], bl[2][2];
#pragma unroll
      for (int m = 0; m < 2; m++)
#pragma unroll
        for (int kh = 0; kh < 2; kh++) {
          int row = wrow + m * 16 + lr;
          int so = ((kh * 4 + kq) * 16) ^ sw0;
          ah[m][kh] = *(const bf16x8*)(base + row * 128 + so);
          al[m][kh] = *(const bf16x8*)(base + (row + 64) * 128 + so);
        }
#pragma unroll
      for (int n = 0; n < 2; n++)
#pragma unroll
        for (int kh = 0; kh < 2; kh++) {
          int row = 128 + wcol + n * 16 + lr;
          int so = ((kh * 4 + kq) * 16) ^ sw0;
          bh[n][kh] = *(const bf16x8*)(base + row * 128 + so);
          bl[n][kh] = *(const bf16x8*)(base + (row + 64) * 128 + so);
        }
#pragma unroll
      for (int kh = 0; kh < 2; kh++)
#pragma unroll
        for (int m = 0; m < 2; m++)
#pragma unroll
          for (int n = 0; n < 2; n++) {
            acc[m][n] = __builtin_amdgcn_mfma_f32_16x16x32_bf16(ah[m][kh], bh[n][kh], acc[m][n], 0, 0, 0);
            acc[m][n] = __builtin_amdgcn_mfma_f32_16x16x32_bf16(al[m][kh], bh[n][kh], acc[m][n], 0, 0, 0);
            acc[m][n] = __builtin_amdgcn_mfma_f32_16x16x32_bf16(ah[m][kh], bl[n][kh], acc[m][n], 0, 0, 0);
          }
    }
  };

  STAGE(0, 0);
  STAGE(1, 1);
  STAGE(2, 2);
  for (int t = 0; t < NT - 3; t++) {
    waitv<2 * UNITS>();
    gbar();
    STAGE((t + 3) & 3, t + 3);
    COMPUTE(t & 3);
  }
  waitv<2 * UNITS>(); gbar(); COMPUTE((NT - 3) & 3);
  waitv<UNITS>();     gbar(); COMPUTE((NT - 2) & 3);
  waitv<0>();         gbar(); COMPUTE((NT - 1) & 3);

  if constexpr (EPI == 0 || EPI == 2) {
    float* Cb = fout + (size_t)(mb * BM + wrow) * 1024 + nb * BN + wcol;
#pragma unroll
    for (int n = 0; n < NR; n++) {
      float blv = (EPI == 2) ? bias[nb * BN + wcol + n * 16 + lr] : 0.f;
#pragma unroll
      for (int m = 0; m < MR; m++)
#pragma unroll
        for (int j = 0; j < 4; j++)
          Cb[(size_t)(m * 16 + kq * 4 + j) * 1024 + n * 16 + lr] = acc[m][n][j] + blv;
    }
  } else if constexpr (EPI == 3) {
    float* Cb = fout + (size_t)(mb * BM + wrow) * 1024 + nb * BN + wcol;
    const int t = (mb * BM) >> 8;
#pragma unroll
    for (int n = 0; n < NR; n++) {
      float s = 0.f, s2 = 0.f;
#pragma unroll
      for (int m = 0; m < MR; m++)
#pragma unroll
        for (int j = 0; j < 4; j++) {
          float v = acc[m][n][j];
          Cb[(size_t)(m * 16 + kq * 4 + j) * 1024 + n * 16 + lr] = v;
          s += v;
          s2 += v * v;
        }
      s += __shfl_xor(s, 16);  s += __shfl_xor(s, 32);
      s2 += __shfl_xor(s2, 16); s2 += __shfl_xor(s2, 32);
      if (kq == 0) {
        int col = nb * BN + wcol + n * 16 + lr;
        atomicAdd(&cbuf[t * 1024 + col], s);
        atomicAdd(&cbuf[131072 + t * 1024 + col], s2);
      }
    }
  } else {
    float* g = (float*)ts;
    __syncthreads();
#pragma unroll
    for (int m = 0; m < 2; m++)
#pragma unroll
      for (int n = 0; n < 2; n++)
#pragma unroll
        for (int j = 0; j < 4; j++)
          g[(wrow + m * 16 + kq * 4 + j) * 65 + wcol + n * 16 + lr] = acc[m][n][j];
    __syncthreads();
    const int n16 = tid & 15;
    const int s = n16 & 7, q = n16 >> 3;
    const int cbase = q * 32 + s;
    const float bi = bias[nb * 64 + cbase];
    const float bf = bias[nb * 64 + cbase + 8];
    const float bg = bias[nb * 64 + cbase + 16];
    const float bo = bias[nb * 64 + cbase + 24];
#pragma unroll
    for (int i2 = 0; i2 < 4; i2++) {
      int br = (tid >> 4) + i2 * 16;
      float xi = g[br * 65 + cbase] + bi;
      float xf = g[br * 65 + cbase + 8] + bf;
      float xg = g[br * 65 + cbase + 16] + bg;
      float xo = g[br * 65 + cbase + 24] + bo;
      int b = mb * 64 + br;
      int col = nb * 16 + n16;
      int cidx = b * 1024 + col;
      float cn = sigf(xf) * cbuf[cidx] + sigf(xi) * tanh_fast(xg);
      float h = sigf(xo) * tanh_fast(cn);
      cbuf[cidx] = cn;
      u16 hi = f2bf(h);
      u16 lo = f2bf(h - bf2f(hi));
      hhi[cidx] = hi;
      hlo[cidx] = lo;
    }
  }
}

// ---- prep kernels (planes pitch 1024) ----

template <bool IMAP, bool WLO>
__global__ __launch_bounds__(256) void prep_split(const float* __restrict__ src,
                                                  u16* __restrict__ hi_p,
                                                  u16* __restrict__ lo_p) {
  int i = blockIdx.x * 256 + threadIdx.x;
  int r = i >> 7, k8 = (i & 127) << 3;
  int orig = IMAP ? origR2(r) : r;
  const float* s = src + (size_t)orig * 1024 + k8;
  u16x8 oh, ol;
#pragma unroll
  for (int e = 0; e < 8; e++) {
    float f = s[e];
    u16 h = f2bf(f);
    oh[e] = h;
    if constexpr (WLO) ol[e] = f2bf(f - bf2f(h));
  }
  *(u16x8*)&hi_p[(size_t)r * 1024 + k8] = oh;
  if constexpr (WLO) *(u16x8*)&lo_p[(size_t)r * 1024 + k8] = ol;
}

// Wlt_hi[k][j] = bf16(W_lin[j][k]) (transpose, hi only — Wc GEMM is hi-only)
__global__ __launch_bounds__(256) void prep_wlt(const float* __restrict__ W,
                                                u16* __restrict__ hi_p) {
  int i = blockIdx.x * 256 + threadIdx.x;
  int k = i >> 7, j8 = (i & 127) << 3;
  u16x8 oh;
#pragma unroll
  for (int e = 0; e < 8; e++) oh[e] = f2bf(W[(size_t)(j8 + e) * 1024 + k]);
  *(u16x8*)&hi_p[(size_t)k * 1024 + j8] = oh;
}

// Beff_hi[R] = bf16(Wc_f32[R] + W_hh[origR2(R)])  (hi plane only)
__global__ __launch_bounds__(256) void prep_beff(const float* __restrict__ Wc,
                                                 const float* __restrict__ Whh,
                                                 u16* __restrict__ hi_p) {
  int i = blockIdx.x * 256 + threadIdx.x;
  int r = i >> 7, k8 = (i & 127) << 3;
  const float* s1 = Wc + (size_t)r * 1024 + k8;
  const float* s2 = Whh + (size_t)origR2(r) * 1024 + k8;
  u16x8 oh;
#pragma unroll
  for (int e = 0; e < 8; e++) oh[e] = f2bf(s1[e] + s2[e]);
  *(u16x8*)&hi_p[(size_t)r * 1024 + k8] = oh;
}

__global__ __launch_bounds__(256) void prep_a0(const float* __restrict__ x0,
                                               const float* __restrict__ h0,
                                               const float* __restrict__ c0,
                                               u16* __restrict__ xhi, u16* __restrict__ xlo,
                                               u16* __restrict__ hhi, u16* __restrict__ hlo,
                                               float* __restrict__ cbuf) {
  int i = blockIdx.x * 256 + threadIdx.x;
  int sel = i >> 15, ii = i & 32767;
  int r = ii >> 7, k8 = (ii & 127) << 3;
  const float* s = (sel ? h0 : x0) + r * 1024 + k8;
  u16* hp = (sel ? hhi : xhi) + r * 1024 + k8;
  u16* lp = (sel ? hlo : xlo) + r * 1024 + k8;
  u16x8 oh, ol;
#pragma unroll
  for (int e = 0; e < 8; e++) {
    float f = s[e];
    u16 h = f2bf(f);
    oh[e] = h;
    ol[e] = f2bf(f - bf2f(h));
  }
  *(u16x8*)hp = oh;
  *(u16x8*)lp = ol;
  if (i < 32768) {
    float4 v0 = *(const float4*)&c0[i * 8];
    float4 v1 = *(const float4*)&c0[i * 8 + 4];
    *(float4*)&cbuf[i * 8] = v0;
    *(float4*)&cbuf[i * 8 + 4] = v1;
  }
}

__global__ __launch_bounds__(256) void prep_bias(const float* __restrict__ Wih,
                                                 const float* __restrict__ b_ih,
                                                 const float* __restrict__ b_hh,
                                                 const float* __restrict__ b_lin,
                                                 float* __restrict__ bc0,
                                                 float* __restrict__ bc1) {
  int wid = threadIdx.x >> 6, lane = threadIdx.x & 63;
  int R = blockIdx.x * 4 + wid;
  int o = origR2(R);
  float p = 0.f;
#pragma unroll
  for (int it = 0; it < 16; it++) p += Wih[(size_t)o * 1024 + lane + it * 64] * b_lin[lane + it * 64];
#pragma unroll
  for (int m = 1; m < 64; m <<= 1) p += __shfl_xor(p, m);
  if (lane == 0) {
    float s = b_ih[o] + b_hh[o];
    bc0[R] = s;
    bc1[R] = s + p;
  }
}

// Normalize in place using precomputed stats (S | S2). 512 blocks (2/CU).
__global__ __launch_bounds__(256) void bn_norm(const float* __restrict__ stats,
                                               float* __restrict__ out) {
  int t = blockIdx.x >> 2, q = blockIdx.x & 3;
  int d = threadIdx.x << 2;
  const float* sp = stats + t * 1024 + d;
  const float* sp2 = stats + 131072 + t * 1024 + d;
  float mean[4], rs[4];
#pragma unroll
  for (int e = 0; e < 4; e++) {
    float mn = sp[e] * (1.f / 256.f);
    float var = fmaxf(sp2[e] * (1.f / 256.f) - mn * mn, 0.f);
    mean[e] = mn;
    rs[e] = rsqrtf(var + 1e-5f);
  }
  float* base = out + (size_t)t * 262144 + q * 65536 + d;
#pragma unroll 4
  for (int b = 0; b < 64; b++) {
    float4 v = *(float4*)(base + b * 1024);
    v.x = (v.x - mean[0]) * rs[0];
    v.y = (v.y - mean[1]) * rs[1];
    v.z = (v.z - mean[2]) * rs[2];
    v.w = (v.w - mean[3]) * rs[3];
    *(float4*)(base + b * 1024) = v;
  }
}

extern "C" void kernel_launch(void* const* d_in, const int* in_sizes, int n_in,
                              void* d_out, int out_size, void* d_ws, size_t ws_size,
                              hipStream_t stream) {
  const float* inputs = (const float*)d_in[0];
  const float* W_ih = (const float*)d_in[1];
  const float* W_hh = (const float*)d_in[2];
  const float* b_ih = (const float*)d_in[3];
  const float* b_hh = (const float*)d_in[4];
  const float* W_lin = (const float*)d_in[5];
  const float* b_lin = (const float*)d_in[6];
  const float* h0 = (const float*)d_in[7];
  const float* c0 = (const float*)d_in[8];
  float* out = (float*)d_out;

  char* ws = (char*)d_ws;
  float* bc0 = (float*)(ws + 0);             // 16,384
  float* bc1 = (float*)(ws + 16384);         // 16,384
  float* cbuf = (float*)(ws + 32768);        // 1,048,576
  u16* Wlin_hi = (u16*)(ws + 1081344);       // 2,097,152
  u16* Beff_hi = (u16*)(ws + 3178496);       // 8,388,608
  u16* xhi = (u16*)(ws + 19955712);          // 524,288
  u16* xlo = (u16*)(ws + 20480000);          // 524,288
  u16* h0hi = (u16*)(ws + 21004288);         // 524,288
  u16* h0lo = (u16*)(ws + 21528576);         // 524,288
  u16* Hlo0 = (u16*)(ws + 22052864);         // 524,288 (step0 writes; unused after)
  u16* Hhi = (u16*)(ws + 23101440);          // 67,108,864 (128 slabs of 512KB)
  // transients aliased inside Hhi (dead after prep / step 0):
  u16* Whh_hi = (u16*)(ws + 23101440 + 2097152);    // slabs 4..19
  u16* Whh_lo = (u16*)(ws + 23101440 + 10485760);   // slabs 20..35
  u16* Wih_hi = (u16*)(ws + 23101440 + 18874368);   // slabs 36..51
  u16* Wih_lo = (u16*)(ws + 23101440 + 27262976);   // slabs 52..67
  u16* Wlt_hi = (u16*)(ws + 23101440 + 35651584);   // slabs 68..71
  float* Wc_f32 = (float*)(ws + 23101440 + 39845888);  // slabs 76..107
  float* stats = (float*)(ws + 90210304);    // 1,048,576 (S | S2)

  hipMemsetAsync(stats, 0, 1048576, stream);
  prep_split<true, true><<<2048, 256, 0, stream>>>(W_ih, Wih_hi, Wih_lo);
  prep_split<true, true><<<2048, 256, 0, stream>>>(W_hh, Whh_hi, Whh_lo);
  prep_split<false, false><<<512, 256, 0, stream>>>(W_lin, Wlin_hi, nullptr);
  prep_wlt<<<512, 256, 0, stream>>>(W_lin, Wlt_hi);
  prep_a0<<<256, 256, 0, stream>>>(inputs, h0, c0, xhi, xlo, h0hi, h0lo, cbuf);
  prep_bias<<<1024, 256, 0, stream>>>(W_ih, b_ih, b_hh, b_lin, bc0, bc1);

  // W_c = W_ih @ W_lin (hi-only bf16; error ~ Beff rounding, under y-floor).
  // M=4096, N=1024, K=1024; MODE2, grid 64mb x 16nb.
  gemmk<64, 64, 16, 2, 0, 0, 16><<<1024, 256, 0, stream>>>(
      Wih_hi, nullptr, nullptr, nullptr, Wlt_hi, nullptr, nullptr, nullptr,
      nullptr, nullptr, nullptr, nullptr, Wc_f32);
  prep_beff<<<2048, 256, 0, stream>>>(Wc_f32, W_hh, Beff_hi);

  // step 0: gates from (x0,h0): two K-phases (x @ Wih, h @ Whh), K=2048 total.
  gemmk<64, 64, 32, 1, 1, 1, 0><<<256, 256, 0, stream>>>(
      xhi, xlo, h0hi, h0lo, Wih_hi, Wih_lo, Whh_hi, Whh_lo,
      bc0, cbuf, Hhi, Hlo0, nullptr);
  // steps 1..127: pure-bf16 stepk8d, gates = h_hi @ Beff_hi.
  for (int t = 1; t < 128; t++) {
    stepk8d<<<256, 512, 0, stream>>>(
        Hhi + (size_t)(t - 1) * SLABH, Beff_hi, bc1, cbuf,
        Hhi + (size_t)t * SLABH);
  }

  // ys' = Hs_hi @ W_lin_hi^T (b_lin cancels in BN). Stats in epilogue.
  // BM=BN=128 (2x arithmetic intensity per LDS byte), SWZ=2: XCD-sliced mb.
  gemmk<128, 128, 16, 2, 3, 2, 0><<<2048, 256, 0, stream>>>(
      Hhi, nullptr, nullptr, nullptr, Wlin_hi, nullptr, nullptr, nullptr,
      nullptr, stats, nullptr, nullptr, out);
  bn_norm<<<512, 256, 0, stream>>>(stats, out);
}